// Round 1
// baseline (515.224 us; speedup 1.0000x reference)
//
#include <hip/hip_runtime.h>
#include <hip/hip_bf16.h>
#include <math.h>

typedef __bf16 bf16x8 __attribute__((ext_vector_type(8)));
typedef float  f32x4  __attribute__((ext_vector_type(4)));

#define N_D 256
#define N_K 64

// ---------------------------------------------------------------------------
// Setup kernel: per-component constants + mu normalized -> bf16 in MFMA
// B-fragment order.  Fragment order: entry index ((step*4 + tile)*64 + lane),
// 8 bf16 each, where comp = tile*16 + (lane&15), d = step*32 + (lane>>4)*8 + j.
// ---------------------------------------------------------------------------
__global__ void vmf_setup_kernel(const float* __restrict__ alpha_logit,
                                 const float* __restrict__ mu_unnorm,
                                 const float* __restrict__ log_kappa,
                                 __bf16* __restrict__ mu_frag,
                                 float* __restrict__ kappa_out,
                                 float* __restrict__ logC_out,
                                 float* __restrict__ la_out)
{
    const int k = blockIdx.x;   // component
    const int t = threadIdx.x;  // d index
    __shared__ float red[256];
    float v = mu_unnorm[k * N_D + t];
    red[t] = v * v;
    __syncthreads();
    for (int s = 128; s > 0; s >>= 1) {
        if (t < s) red[t] += red[t + s];
        __syncthreads();
    }
    float nrm = fmaxf(sqrtf(red[0]), 1e-12f);
    float mun = v / nrm;

    // scatter into B-fragment layout
    int step = t >> 5;
    int tile = k >> 4;
    int lane = (k & 15) | (((t >> 3) & 3) << 4);
    int j    = t & 7;
    mu_frag[(((step * 4 + tile) * 64 + lane) << 3) + j] = (__bf16)mun;

    if (t == 0) {
        // kappa and logC (double precision; trivial cost)
        double kap = exp((double)log_kappa[k]) + 1e-6;
        const double s_ = 127.0;            // 0.5*256 - 1
        double lk2 = log(kap * 0.5);
        double tmax = -1e300;
        for (int m = 0; m < 64; ++m) {
            double term = (2.0 * m + s_) * lk2 - lgamma((double)m + 1.0)
                        - lgamma((double)m + s_ + 1.0);
            tmax = fmax(tmax, term);
        }
        double ssum = 0.0;
        for (int m = 0; m < 64; ++m) {
            double term = (2.0 * m + s_) * lk2 - lgamma((double)m + 1.0)
                        - lgamma((double)m + s_ + 1.0);
            ssum += exp(term - tmax);
        }
        double logI = tmax + log(ssum);
        double logC = 256.0 * (-0.9189385332046727) + s_ * log(kap) - logI;
        kappa_out[k] = (float)kap;
        logC_out[k]  = (float)logC;
    }
    if (k == 0 && t == 1) {
        // log_softmax over 64 alpha logits (redundant-cheap, one thread)
        float mx = -1e30f;
        for (int i = 0; i < N_K; ++i) mx = fmaxf(mx, alpha_logit[i]);
        float sm = 0.f;
        for (int i = 0; i < N_K; ++i) sm += expf(alpha_logit[i] - mx);
        float lsum = logf(sm);
        for (int i = 0; i < N_K; ++i) la_out[i] = alpha_logit[i] - mx - lsum;
    }
}

// ---------------------------------------------------------------------------
// Main kernel: each wave = 16 rows x all 64 components.
// A-frag: m = lane&15 (row), k = (lane>>4)*8 + j   [measured layout]
// C-frag: col = lane&15, row = (lane>>4)*4 + reg   [measured layout]
// ---------------------------------------------------------------------------
__global__ __launch_bounds__(256)
void vmf_main_kernel(const float* __restrict__ x,
                     const bf16x8* __restrict__ mu_frag,
                     const float* __restrict__ kappa,
                     const float* __restrict__ logC,
                     const float* __restrict__ la,
                     float* __restrict__ out_ll,
                     float* __restrict__ out_lp)
{
    const int lane = threadIdx.x & 63;
    const int wave = threadIdx.x >> 6;
    const int quad = lane >> 4;
    const int l16  = lane & 15;
    const int rowbase = blockIdx.x * 64 + wave * 16;
    const int arow = rowbase + l16;

    f32x4 acc0 = {0.f, 0.f, 0.f, 0.f};
    f32x4 acc1 = {0.f, 0.f, 0.f, 0.f};
    f32x4 acc2 = {0.f, 0.f, 0.f, 0.f};
    f32x4 acc3 = {0.f, 0.f, 0.f, 0.f};

    const float* xp = x + (size_t)arow * N_D + quad * 8;

    #pragma unroll
    for (int s = 0; s < 8; ++s) {
        float4 lo = *(const float4*)(xp + s * 32);
        float4 hi = *(const float4*)(xp + s * 32 + 4);
        bf16x8 a;
        a[0] = (__bf16)lo.x; a[1] = (__bf16)lo.y;
        a[2] = (__bf16)lo.z; a[3] = (__bf16)lo.w;
        a[4] = (__bf16)hi.x; a[5] = (__bf16)hi.y;
        a[6] = (__bf16)hi.z; a[7] = (__bf16)hi.w;
        bf16x8 b0 = mu_frag[(s * 4 + 0) * 64 + lane];
        bf16x8 b1 = mu_frag[(s * 4 + 1) * 64 + lane];
        bf16x8 b2 = mu_frag[(s * 4 + 2) * 64 + lane];
        bf16x8 b3 = mu_frag[(s * 4 + 3) * 64 + lane];
        acc0 = __builtin_amdgcn_mfma_f32_16x16x32_bf16(a, b0, acc0, 0, 0, 0);
        acc1 = __builtin_amdgcn_mfma_f32_16x16x32_bf16(a, b1, acc1, 0, 0, 0);
        acc2 = __builtin_amdgcn_mfma_f32_16x16x32_bf16(a, b2, acc2, 0, 0, 0);
        acc3 = __builtin_amdgcn_mfma_f32_16x16x32_bf16(a, b3, acc3, 0, 0, 0);
    }

    // per-lane column constants (col = t*16 + l16)
    float kap[4], lc[4], lat[4];
    #pragma unroll
    for (int t = 0; t < 4; ++t) {
        int c = t * 16 + l16;
        kap[t] = kappa[c];
        lc[t]  = logC[c];
        lat[t] = la[c];
    }

    f32x4 accs[4] = {acc0, acc1, acc2, acc3};

    #pragma unroll
    for (int reg = 0; reg < 4; ++reg) {
        const int row = rowbase + quad * 4 + reg;
        float vv[4];
        #pragma unroll
        for (int t = 0; t < 4; ++t) {
            float d  = accs[t][reg];
            float lp = fmaf(kap[t], d, lc[t]);
            out_lp[(size_t)row * N_K + t * 16 + l16] = lp;
            vv[t] = lp + lat[t];
        }
        // row-wise logsumexp over 64 cols: 4 local + 16-lane butterfly
        float m = fmaxf(fmaxf(vv[0], vv[1]), fmaxf(vv[2], vv[3]));
        #pragma unroll
        for (int off = 1; off <= 8; off <<= 1)
            m = fmaxf(m, __shfl_xor(m, off, 64));
        float ssum = expf(vv[0] - m) + expf(vv[1] - m)
                   + expf(vv[2] - m) + expf(vv[3] - m);
        #pragma unroll
        for (int off = 1; off <= 8; off <<= 1)
            ssum += __shfl_xor(ssum, off, 64);
        if (l16 == 0)
            out_ll[row] = m + logf(ssum);
    }
}

extern "C" void kernel_launch(void* const* d_in, const int* in_sizes, int n_in,
                              void* d_out, int out_size, void* d_ws, size_t ws_size,
                              hipStream_t stream)
{
    (void)n_in; (void)out_size; (void)ws_size;
    const float* x           = (const float*)d_in[0];
    const float* alpha_logit = (const float*)d_in[1];
    const float* mu_unnorm   = (const float*)d_in[2];
    const float* log_kappa   = (const float*)d_in[3];
    const int N = in_sizes[0] / N_D;

    char* ws = (char*)d_ws;
    __bf16* mu_frag = (__bf16*)ws;                    // 32768 B
    float*  kappa   = (float*)(ws + 32768);           // 256 B
    float*  logC    = (float*)(ws + 32768 + 256);     // 256 B
    float*  la      = (float*)(ws + 32768 + 512);     // 256 B

    float* out_ll = (float*)d_out;       // (N,)
    float* out_lp = out_ll + N;          // (N, 64)

    hipLaunchKernelGGL(vmf_setup_kernel, dim3(N_K), dim3(N_D), 0, stream,
                       alpha_logit, mu_unnorm, log_kappa, mu_frag, kappa, logC, la);
    hipLaunchKernelGGL(vmf_main_kernel, dim3(N / 64), dim3(256), 0, stream,
                       x, (const bf16x8*)mu_frag, kappa, logC, la, out_ll, out_lp);
}

// Round 2
// 395.883 us; speedup vs baseline: 1.3015x; 1.3015x over previous
//
#include <hip/hip_runtime.h>
#include <hip/hip_bf16.h>
#include <math.h>

typedef __bf16 bf16x8 __attribute__((ext_vector_type(8)));
typedef float  f32x4  __attribute__((ext_vector_type(4)));

#define N_D 256
#define N_K 64

// ---------------------------------------------------------------------------
// Setup kernel: per-component constants + mu normalized -> bf16 in MFMA
// B-fragment order.  Fragment order: entry index ((step*4 + tile)*64 + lane),
// 8 bf16 each, where comp = tile*16 + (lane&15), d = step*32 + (lane>>4)*8 + j.
// Bessel series is parallelized: thread t<64 computes term t (2 f64 lgamma),
// tree-reduced in LDS.  (Previous version serialized 512 lgamma on one lane
// -> ~150us; this is the main fix this round.)
// ---------------------------------------------------------------------------
__global__ void vmf_setup_kernel(const float* __restrict__ alpha_logit,
                                 const float* __restrict__ mu_unnorm,
                                 const float* __restrict__ log_kappa,
                                 __bf16* __restrict__ mu_frag,
                                 float* __restrict__ kappa_out,
                                 float* __restrict__ logC_out,
                                 float* __restrict__ la_out)
{
    const int k = blockIdx.x;   // component
    const int t = threadIdx.x;  // d index
    __shared__ float  red[256];
    __shared__ double dterm[64];
    __shared__ double dred[64];

    float v = mu_unnorm[k * N_D + t];
    red[t] = v * v;
    __syncthreads();
    for (int s = 128; s > 0; s >>= 1) {
        if (t < s) red[t] += red[t + s];
        __syncthreads();
    }
    float nrm = fmaxf(sqrtf(red[0]), 1e-12f);
    float mun = v / nrm;

    // scatter into B-fragment layout
    {
        int step = t >> 5;
        int tile = k >> 4;
        int lane = (k & 15) | (((t >> 3) & 3) << 4);
        int j    = t & 7;
        mu_frag[(((step * 4 + tile) * 64 + lane) << 3) + j] = (__bf16)mun;
    }

    // ---- logC via 64-term ascending series, parallel over terms ----
    const double kap = exp((double)log_kappa[k]) + 1e-6;
    const double s_  = 127.0;                 // 0.5*256 - 1
    if (t < 64) {
        double lk2 = log(kap * 0.5);
        double m   = (double)t;
        dterm[t] = (2.0 * m + s_) * lk2 - lgamma(m + 1.0) - lgamma(m + s_ + 1.0);
        dred[t]  = dterm[t];
    }
    __syncthreads();
    for (int s = 32; s > 0; s >>= 1) {
        if (t < s) dred[t] = fmax(dred[t], dred[t + s]);
        __syncthreads();
    }
    double tmax = dred[0];
    __syncthreads();
    if (t < 64) dred[t] = exp(dterm[t] - tmax);
    __syncthreads();
    for (int s = 32; s > 0; s >>= 1) {
        if (t < s) dred[t] += dred[t + s];
        __syncthreads();
    }
    if (t == 0) {
        double logI = tmax + log(dred[0]);
        double logC = 256.0 * (-0.9189385332046727) + s_ * log(kap) - logI;
        kappa_out[k] = (float)kap;
        logC_out[k]  = (float)logC;
    }
    if (k == 0 && t == 64) {
        // log_softmax over 64 alpha logits (one thread, trivial)
        float mx = -1e30f;
        for (int i = 0; i < N_K; ++i) mx = fmaxf(mx, alpha_logit[i]);
        float sm = 0.f;
        for (int i = 0; i < N_K; ++i) sm += expf(alpha_logit[i] - mx);
        float lsum = logf(sm);
        for (int i = 0; i < N_K; ++i) la_out[i] = alpha_logit[i] - mx - lsum;
    }
}

// ---------------------------------------------------------------------------
// Main kernel: each wave = 16 rows x all 64 components.
// A-frag: m = lane&15 (row), k = (lane>>4)*8 + j   [measured layout]
// C-frag: col = lane&15, row = (lane>>4)*4 + reg   [measured layout]
// ---------------------------------------------------------------------------
__global__ __launch_bounds__(256)
void vmf_main_kernel(const float* __restrict__ x,
                     const bf16x8* __restrict__ mu_frag,
                     const float* __restrict__ kappa,
                     const float* __restrict__ logC,
                     const float* __restrict__ la,
                     float* __restrict__ out_ll,
                     float* __restrict__ out_lp)
{
    const int lane = threadIdx.x & 63;
    const int wave = threadIdx.x >> 6;
    const int quad = lane >> 4;
    const int l16  = lane & 15;
    const int rowbase = blockIdx.x * 64 + wave * 16;
    const int arow = rowbase + l16;

    f32x4 acc0 = {0.f, 0.f, 0.f, 0.f};
    f32x4 acc1 = {0.f, 0.f, 0.f, 0.f};
    f32x4 acc2 = {0.f, 0.f, 0.f, 0.f};
    f32x4 acc3 = {0.f, 0.f, 0.f, 0.f};

    const float* xp = x + (size_t)arow * N_D + quad * 8;

    #pragma unroll
    for (int s = 0; s < 8; ++s) {
        float4 lo = *(const float4*)(xp + s * 32);
        float4 hi = *(const float4*)(xp + s * 32 + 4);
        bf16x8 a;
        a[0] = (__bf16)lo.x; a[1] = (__bf16)lo.y;
        a[2] = (__bf16)lo.z; a[3] = (__bf16)lo.w;
        a[4] = (__bf16)hi.x; a[5] = (__bf16)hi.y;
        a[6] = (__bf16)hi.z; a[7] = (__bf16)hi.w;
        bf16x8 b0 = mu_frag[(s * 4 + 0) * 64 + lane];
        bf16x8 b1 = mu_frag[(s * 4 + 1) * 64 + lane];
        bf16x8 b2 = mu_frag[(s * 4 + 2) * 64 + lane];
        bf16x8 b3 = mu_frag[(s * 4 + 3) * 64 + lane];
        acc0 = __builtin_amdgcn_mfma_f32_16x16x32_bf16(a, b0, acc0, 0, 0, 0);
        acc1 = __builtin_amdgcn_mfma_f32_16x16x32_bf16(a, b1, acc1, 0, 0, 0);
        acc2 = __builtin_amdgcn_mfma_f32_16x16x32_bf16(a, b2, acc2, 0, 0, 0);
        acc3 = __builtin_amdgcn_mfma_f32_16x16x32_bf16(a, b3, acc3, 0, 0, 0);
    }

    // per-lane column constants (col = t*16 + l16)
    float kap[4], lc[4], lat[4];
    #pragma unroll
    for (int t = 0; t < 4; ++t) {
        int c = t * 16 + l16;
        kap[t] = kappa[c];
        lc[t]  = logC[c];
        lat[t] = la[c];
    }

    f32x4 accs[4] = {acc0, acc1, acc2, acc3};

    #pragma unroll
    for (int reg = 0; reg < 4; ++reg) {
        const int row = rowbase + quad * 4 + reg;
        float vv[4];
        #pragma unroll
        for (int t = 0; t < 4; ++t) {
            float d  = accs[t][reg];
            float lp = fmaf(kap[t], d, lc[t]);
            out_lp[(size_t)row * N_K + t * 16 + l16] = lp;
            vv[t] = lp + lat[t];
        }
        // row-wise logsumexp over 64 cols: 4 local + 16-lane butterfly
        float m = fmaxf(fmaxf(vv[0], vv[1]), fmaxf(vv[2], vv[3]));
        #pragma unroll
        for (int off = 1; off <= 8; off <<= 1)
            m = fmaxf(m, __shfl_xor(m, off, 64));
        float ssum = expf(vv[0] - m) + expf(vv[1] - m)
                   + expf(vv[2] - m) + expf(vv[3] - m);
        #pragma unroll
        for (int off = 1; off <= 8; off <<= 1)
            ssum += __shfl_xor(ssum, off, 64);
        if (l16 == 0)
            out_ll[row] = m + logf(ssum);
    }
}

extern "C" void kernel_launch(void* const* d_in, const int* in_sizes, int n_in,
                              void* d_out, int out_size, void* d_ws, size_t ws_size,
                              hipStream_t stream)
{
    (void)n_in; (void)out_size; (void)ws_size;
    const float* x           = (const float*)d_in[0];
    const float* alpha_logit = (const float*)d_in[1];
    const float* mu_unnorm   = (const float*)d_in[2];
    const float* log_kappa   = (const float*)d_in[3];
    const int N = in_sizes[0] / N_D;

    char* ws = (char*)d_ws;
    __bf16* mu_frag = (__bf16*)ws;                    // 32768 B
    float*  kappa   = (float*)(ws + 32768);           // 256 B
    float*  logC    = (float*)(ws + 32768 + 256);     // 256 B
    float*  la      = (float*)(ws + 32768 + 512);     // 256 B

    float* out_ll = (float*)d_out;       // (N,)
    float* out_lp = out_ll + N;          // (N, 64)

    hipLaunchKernelGGL(vmf_setup_kernel, dim3(N_K), dim3(N_D), 0, stream,
                       alpha_logit, mu_unnorm, log_kappa, mu_frag, kappa, logC, la);
    hipLaunchKernelGGL(vmf_main_kernel, dim3(N / 64), dim3(256), 0, stream,
                       x, (const bf16x8*)mu_frag, kappa, logC, la, out_ll, out_lp);
}

// Round 4
// 384.751 us; speedup vs baseline: 1.3391x; 1.0289x over previous
//
#include <hip/hip_runtime.h>
#include <hip/hip_bf16.h>
#include <math.h>

typedef __bf16 bf16x8 __attribute__((ext_vector_type(8)));
typedef float  f32x4  __attribute__((ext_vector_type(4)));

#define N_D 256
#define N_K 64

// ---------------------------------------------------------------------------
// Setup kernel: per-component constants + mu normalized -> bf16 in MFMA
// B-fragment order.  Fragment order: entry index ((step*4 + tile)*64 + lane),
// 8 bf16 each, where comp = tile*16 + (lane&15), d = step*32 + (lane>>4)*8 + j.
// Bessel series parallel over terms: thread t<64 does 2 f64 lgamma, LDS tree
// reduction.  (R1->R2: this dropped dur_us by 119us.)
// ---------------------------------------------------------------------------
__global__ void vmf_setup_kernel(const float* __restrict__ alpha_logit,
                                 const float* __restrict__ mu_unnorm,
                                 const float* __restrict__ log_kappa,
                                 __bf16* __restrict__ mu_frag,
                                 float* __restrict__ kappa_out,
                                 float* __restrict__ logC_out,
                                 float* __restrict__ la_out)
{
    const int k = blockIdx.x;   // component
    const int t = threadIdx.x;  // d index
    __shared__ float  red[256];
    __shared__ double dterm[64];
    __shared__ double dred[64];

    float v = mu_unnorm[k * N_D + t];
    red[t] = v * v;
    __syncthreads();
    for (int s = 128; s > 0; s >>= 1) {
        if (t < s) red[t] += red[t + s];
        __syncthreads();
    }
    float nrm = fmaxf(sqrtf(red[0]), 1e-12f);
    float mun = v / nrm;

    // scatter into B-fragment layout
    {
        int step = t >> 5;
        int tile = k >> 4;
        int lane = (k & 15) | (((t >> 3) & 3) << 4);
        int j    = t & 7;
        mu_frag[(((step * 4 + tile) * 64 + lane) << 3) + j] = (__bf16)mun;
    }

    // ---- logC via 64-term ascending series, parallel over terms ----
    const double kap = exp((double)log_kappa[k]) + 1e-6;
    const double s_  = 127.0;                 // 0.5*256 - 1
    if (t < 64) {
        double lk2 = log(kap * 0.5);
        double m   = (double)t;
        dterm[t] = (2.0 * m + s_) * lk2 - lgamma(m + 1.0) - lgamma(m + s_ + 1.0);
        dred[t]  = dterm[t];
    }
    __syncthreads();
    for (int s = 32; s > 0; s >>= 1) {
        if (t < s) dred[t] = fmax(dred[t], dred[t + s]);
        __syncthreads();
    }
    double tmax = dred[0];
    __syncthreads();
    if (t < 64) dred[t] = exp(dterm[t] - tmax);
    __syncthreads();
    for (int s = 32; s > 0; s >>= 1) {
        if (t < s) dred[t] += dred[t + s];
        __syncthreads();
    }
    if (t == 0) {
        double logI = tmax + log(dred[0]);
        double logC = 256.0 * (-0.9189385332046727) + s_ * log(kap) - logI;
        kappa_out[k] = (float)kap;
        logC_out[k]  = (float)logC;
    }
    if (k == 0 && t == 64) {
        // log_softmax over 64 alpha logits (one thread, trivial)
        float mx = -1e30f;
        for (int i = 0; i < N_K; ++i) mx = fmaxf(mx, alpha_logit[i]);
        float sm = 0.f;
        for (int i = 0; i < N_K; ++i) sm += expf(alpha_logit[i] - mx);
        float lsum = logf(sm);
        for (int i = 0; i < N_K; ++i) la_out[i] = alpha_logit[i] - mx - lsum;
    }
}

// ---------------------------------------------------------------------------
// Main kernel: each wave = 16 rows x all 64 components.
// A-frag: m = lane&15 (row), k = (lane>>4)*8 + j   [measured layout]
// C-frag: col = lane&15, row = (lane>>4)*4 + reg   [measured layout]
// mu fragments staged in LDS once per block (32 KB), read via ds_read_b128
// (16 B/lane contiguous -> conflict-free).  x loads + lp stores nontemporal
// (stream-once data; keep L2 for mu/broadcast).  Nontemporal builtins need
// ext_vector_type pointers (HIP_vector_type float4 rejected by clang).
// ---------------------------------------------------------------------------
__global__ __launch_bounds__(256)
void vmf_main_kernel(const float* __restrict__ x,
                     const bf16x8* __restrict__ mu_frag,
                     const float* __restrict__ kappa,
                     const float* __restrict__ logC,
                     const float* __restrict__ la,
                     float* __restrict__ out_ll,
                     float* __restrict__ out_lp)
{
    __shared__ bf16x8 smu[2048];   // 32 frag-groups x 64 lanes x 16 B = 32 KB

    const int tid  = threadIdx.x;
    const int lane = tid & 63;
    const int wave = tid >> 6;
    const int quad = lane >> 4;
    const int l16  = lane & 15;
    const int rowbase = blockIdx.x * 64 + wave * 16;
    const int arow = rowbase + l16;

    // cooperative stage of all B fragments into LDS
    #pragma unroll
    for (int i = 0; i < 8; ++i)
        smu[i * 256 + tid] = mu_frag[i * 256 + tid];
    __syncthreads();

    f32x4 acc0 = {0.f, 0.f, 0.f, 0.f};
    f32x4 acc1 = {0.f, 0.f, 0.f, 0.f};
    f32x4 acc2 = {0.f, 0.f, 0.f, 0.f};
    f32x4 acc3 = {0.f, 0.f, 0.f, 0.f};

    const float* xp = x + (size_t)arow * N_D + quad * 8;

    #pragma unroll
    for (int s = 0; s < 8; ++s) {
        f32x4 lo = __builtin_nontemporal_load((const f32x4*)(xp + s * 32));
        f32x4 hi = __builtin_nontemporal_load((const f32x4*)(xp + s * 32 + 4));
        bf16x8 a;
        a[0] = (__bf16)lo[0]; a[1] = (__bf16)lo[1];
        a[2] = (__bf16)lo[2]; a[3] = (__bf16)lo[3];
        a[4] = (__bf16)hi[0]; a[5] = (__bf16)hi[1];
        a[6] = (__bf16)hi[2]; a[7] = (__bf16)hi[3];
        bf16x8 b0 = smu[(s * 4 + 0) * 64 + lane];
        bf16x8 b1 = smu[(s * 4 + 1) * 64 + lane];
        bf16x8 b2 = smu[(s * 4 + 2) * 64 + lane];
        bf16x8 b3 = smu[(s * 4 + 3) * 64 + lane];
        acc0 = __builtin_amdgcn_mfma_f32_16x16x32_bf16(a, b0, acc0, 0, 0, 0);
        acc1 = __builtin_amdgcn_mfma_f32_16x16x32_bf16(a, b1, acc1, 0, 0, 0);
        acc2 = __builtin_amdgcn_mfma_f32_16x16x32_bf16(a, b2, acc2, 0, 0, 0);
        acc3 = __builtin_amdgcn_mfma_f32_16x16x32_bf16(a, b3, acc3, 0, 0, 0);
    }

    // per-lane column constants (col = t*16 + l16)
    float kap[4], lc[4], lat[4];
    #pragma unroll
    for (int t = 0; t < 4; ++t) {
        int c = t * 16 + l16;
        kap[t] = kappa[c];
        lc[t]  = logC[c];
        lat[t] = la[c];
    }

    f32x4 accs[4] = {acc0, acc1, acc2, acc3};

    #pragma unroll
    for (int reg = 0; reg < 4; ++reg) {
        const int row = rowbase + quad * 4 + reg;
        float vv[4];
        #pragma unroll
        for (int t = 0; t < 4; ++t) {
            float d  = accs[t][reg];
            float lp = fmaf(kap[t], d, lc[t]);
            __builtin_nontemporal_store(lp, &out_lp[(size_t)row * N_K + t * 16 + l16]);
            vv[t] = lp + lat[t];
        }
        // row-wise logsumexp over 64 cols: 4 local + 16-lane butterfly
        float m = fmaxf(fmaxf(vv[0], vv[1]), fmaxf(vv[2], vv[3]));
        #pragma unroll
        for (int off = 1; off <= 8; off <<= 1)
            m = fmaxf(m, __shfl_xor(m, off, 64));
        float ssum = expf(vv[0] - m) + expf(vv[1] - m)
                   + expf(vv[2] - m) + expf(vv[3] - m);
        #pragma unroll
        for (int off = 1; off <= 8; off <<= 1)
            ssum += __shfl_xor(ssum, off, 64);
        if (l16 == 0)
            out_ll[row] = m + logf(ssum);
    }
}

extern "C" void kernel_launch(void* const* d_in, const int* in_sizes, int n_in,
                              void* d_out, int out_size, void* d_ws, size_t ws_size,
                              hipStream_t stream)
{
    (void)n_in; (void)out_size; (void)ws_size;
    const float* x           = (const float*)d_in[0];
    const float* alpha_logit = (const float*)d_in[1];
    const float* mu_unnorm   = (const float*)d_in[2];
    const float* log_kappa   = (const float*)d_in[3];
    const int N = in_sizes[0] / N_D;

    char* ws = (char*)d_ws;
    __bf16* mu_frag = (__bf16*)ws;                    // 32768 B
    float*  kappa   = (float*)(ws + 32768);           // 256 B
    float*  logC    = (float*)(ws + 32768 + 256);     // 256 B
    float*  la      = (float*)(ws + 32768 + 512);     // 256 B

    float* out_ll = (float*)d_out;       // (N,)
    float* out_lp = out_ll + N;          // (N, 64)

    hipLaunchKernelGGL(vmf_setup_kernel, dim3(N_K), dim3(N_D), 0, stream,
                       alpha_logit, mu_unnorm, log_kappa, mu_frag, kappa, logC, la);
    hipLaunchKernelGGL(vmf_main_kernel, dim3(N / 64), dim3(256), 0, stream,
                       x, (const bf16x8*)mu_frag, kappa, logC, la, out_ll, out_lp);
}